// Round 7
// baseline (106.172 us; speedup 1.0000x reference)
//
#include <hip/hip_runtime.h>

#define Bn 4
#define Cdim 64
#define INTER 32
#define Ln 4096
#define LOG2E 1.44269504088896340736f

typedef _Float16 half_t;
typedef __attribute__((ext_vector_type(8))) _Float16 half8v;
typedef __attribute__((ext_vector_type(4))) short short4v;
typedef __attribute__((ext_vector_type(8))) short short8v;
typedef __attribute__((ext_vector_type(4))) float f32x4;

__device__ __forceinline__ unsigned short f2bf(float f) {
    unsigned u = __float_as_uint(f);
    u += 0x7fffu + ((u >> 16) & 1u);
    return (unsigned short)(u >> 16);
}
__device__ __forceinline__ unsigned pack_bf(float a, float b) {
    unsigned ua = __float_as_uint(a) + 0x8000u;
    unsigned ub = __float_as_uint(b) + 0x8000u;
    return __builtin_amdgcn_perm(ub, ua, 0x07060302);
}
__device__ __forceinline__ void gll16(const void* g, void* l) {
    __builtin_amdgcn_global_load_lds(
        (const __attribute__((address_space(1))) unsigned int*)g,
        (__attribute__((address_space(3))) unsigned int*)l, 16, 0, 0);
}
__device__ __forceinline__ half8v cvt8(const float* p, float scale) {
    float4 f0 = *(const float4*)p;
    float4 f1 = *(const float4*)(p + 4);
    half_t h[8];
    h[0] = (half_t)(f0.x * scale); h[1] = (half_t)(f0.y * scale);
    h[2] = (half_t)(f0.z * scale); h[3] = (half_t)(f0.w * scale);
    h[4] = (half_t)(f1.x * scale); h[5] = (half_t)(f1.y * scale);
    h[6] = (half_t)(f1.z * scale); h[7] = (half_t)(f1.w * scale);
    half8v r;
    __builtin_memcpy(&r, h, 16);
    return r;
}

// ---------------------------------------------------------------------------
// proj (MFMA): [96ch][64l] = W * x-tile; weights read+converted directly from
// global (no setup kernel). Grid Bn*64 x 192 (3 waves: theta / phi / g).
// Outputs in MFMA fragment layout:
//   thfrag/phfrag: [b][l16][lane][8 f16], gfrag: [b][k16][lane][8 bf16].
// ---------------------------------------------------------------------------
__global__ __launch_bounds__(192) void proj_kernel(
        const float* __restrict__ x,
        const float* __restrict__ g_w, const float* __restrict__ g_b,
        const float* __restrict__ th_w, const float* __restrict__ th_b,
        const float* __restrict__ ph_w, const float* __restrict__ ph_b,
        half_t* __restrict__ thfrag, half_t* __restrict__ phfrag,
        unsigned short* __restrict__ gfrag) {
    __shared__ half_t sx[64][72];        // [l][c]; 144B rows (16B-multiple)
    __shared__ unsigned short sg[2048];  // g-frag staging (4KB)
    int tid = threadIdx.x;
    int b = blockIdx.x >> 6;
    int l0 = (blockIdx.x & 63) << 6;

    for (int i = tid; i < 1024; i += 192) {
        int c = i >> 4, lq = (i & 15) << 2;
        float4 v = *(const float4*)&x[(size_t)(b * 64 + c) * Ln + l0 + lq];
        sx[lq + 0][c] = (half_t)v.x;
        sx[lq + 1][c] = (half_t)v.y;
        sx[lq + 2][c] = (half_t)v.z;
        sx[lq + 3][c] = (half_t)v.w;
    }
    __syncthreads();

    int lane = tid & 63, grp = tid >> 6;    // 0=theta 1=phi 2=g
    int l15 = lane & 15, quad = lane >> 4;

    const float* Wsrc = (grp == 0) ? th_w : (grp == 1) ? ph_w : g_w;
    const float* bsrc = (grp == 0) ? th_b : (grp == 1) ? ph_b : g_b;
    float scale = (grp == 0) ? LOG2E : 1.0f;

    half8v wA[2][2];
#pragma unroll
    for (int mf = 0; mf < 2; mf++)
#pragma unroll
        for (int kk = 0; kk < 2; kk++)
            wA[mf][kk] = cvt8(&Wsrc[(mf * 16 + l15) * 64 + kk * 32 + quad * 8], scale);
    half8v xB[4][2];
#pragma unroll
    for (int nf = 0; nf < 4; nf++)
#pragma unroll
        for (int kk = 0; kk < 2; kk++)
            xB[nf][kk] = *(const half8v*)&sx[nf * 16 + l15][kk * 32 + quad * 8];

    f32x4 acc[2][4];
    const f32x4 z = {0.f, 0.f, 0.f, 0.f};
#pragma unroll
    for (int mf = 0; mf < 2; mf++)
#pragma unroll
        for (int nf = 0; nf < 4; nf++) {
            f32x4 a = __builtin_amdgcn_mfma_f32_16x16x32_f16(wA[mf][0], xB[nf][0], z, 0, 0, 0);
            acc[mf][nf] = __builtin_amdgcn_mfma_f32_16x16x32_f16(wA[mf][1], xB[nf][1], a, 0, 0, 0);
        }
#pragma unroll
    for (int mf = 0; mf < 2; mf++) {
        float4 bv = *(const float4*)&bsrc[mf * 16 + quad * 4];
        float s0 = bv.x * scale, s1 = bv.y * scale, s2 = bv.z * scale, s3 = bv.w * scale;
#pragma unroll
        for (int nf = 0; nf < 4; nf++) {
            acc[mf][nf][0] += s0; acc[mf][nf][1] += s1;
            acc[mf][nf][2] += s2; acc[mf][nf][3] += s3;
        }
    }

    if (grp < 2) {
        half_t* F = (grp == 0) ? thfrag : phfrag;
#pragma unroll
        for (int mf = 0; mf < 2; mf++)
#pragma unroll
            for (int nf = 0; nf < 4; nf++) {
                half_t h[4];
                h[0] = (half_t)acc[mf][nf][0]; h[1] = (half_t)acc[mf][nf][1];
                h[2] = (half_t)acc[mf][nf][2]; h[3] = (half_t)acc[mf][nf][3];
                uint2 v;
                __builtin_memcpy(&v, h, 8);
                size_t u = (size_t)(b * 256 + (l0 >> 4) + nf) * 64 +
                           l15 + 16 * (mf * 2 + (quad >> 1));
                *(uint2*)(F + u * 8 + (quad & 1) * 4) = v;
            }
    } else {
#pragma unroll
        for (int mf = 0; mf < 2; mf++)
#pragma unroll
            for (int nf = 0; nf < 4; nf++)
#pragma unroll
                for (int r = 0; r < 4; r++) {
                    int lu = nf * 64 + (quad * 4 + r) + 16 * (l15 >> 2);
                    sg[lu * 8 + mf * 4 + (l15 & 3)] = f2bf(acc[mf][nf][r]);
                }
        __builtin_amdgcn_s_waitcnt(0);
        size_t base = (size_t)(b * 256 + (l0 >> 4)) * 512;
#pragma unroll
        for (int s = 0; s < 4; s++) {
            int i = lane + s * 64;
            uint4 v = ((const uint4*)sg)[i];
            *(uint4*)(gfrag + base + (size_t)i * 8) = v;
        }
    }
}

// ---------------------------------------------------------------------------
// attn: 16 q per wave (low VGPR -> 8 blocks/CU), KC=16, LDS-staged (dbuf,
// global_load_lds). Denominator on MFMA pipe (ones-row). Epilogue transposes
// acc through padded LDS -> part stored as [b][kc][q][c32] rows, fully
// coalesced 16B/lane. Grid Bn*64*KC x 256.
// ---------------------------------------------------------------------------
__global__ __launch_bounds__(256, 8) void attn_kernel(
        const half_t* __restrict__ thfrag, const half_t* __restrict__ phfrag,
        const unsigned short* __restrict__ gfrag,
        unsigned short* __restrict__ part, float* __restrict__ Sden,
        int KC, int CH) {
    __shared__ uint4 sbuf[2][512];   // 16KB: [buf][phi 4KB | g 4KB]

    int tid = threadIdx.x, lane = tid & 63, widx = tid >> 6;
    int l15 = lane & 15, quad = lane >> 4;

    int blk = blockIdx.x;
    int b = blk / (64 * KC);
    int rem = blk % (64 * KC);
    int qblk = rem / KC, kc = rem % KC;
    int qbase = qblk * 64 + widx * 16;
    int k0 = kc * CH;

    half8v th = *(const half8v*)(thfrag +
                                 ((size_t)(b * 256 + qblk * 4 + widx) * 64 + lane) * 8);

    unsigned short oh = (l15 == 0) ? 0x3F80 : 0;
    short4v ones;
    ones[0] = (short)oh; ones[1] = (short)oh; ones[2] = (short)oh; ones[3] = (short)oh;

    f32x4 acc0 = {0.f, 0.f, 0.f, 0.f};
    f32x4 acc1 = {0.f, 0.f, 0.f, 0.f};
    f32x4 accd = {0.f, 0.f, 0.f, 0.f};

    const char* phsrc = (const char*)(phfrag + (size_t)b * 256 * 512);
    const char* gsrc  = (const char*)(gfrag + (size_t)b * 256 * 512);
    const f32x4 z = {0.f, 0.f, 0.f, 0.f};

    gll16(phsrc + (size_t)(k0 >> 4) * 1024 + tid * 16, (char*)&sbuf[0][0] + tid * 16);
    gll16(gsrc + (size_t)(k0 >> 4) * 1024 + tid * 16, (char*)&sbuf[0][256] + tid * 16);
    __syncthreads();

    int cb = 0;
    for (int kt = k0; kt < k0 + CH; kt += 64) {
        if (kt + 64 < k0 + CH) {
            gll16(phsrc + (size_t)((kt + 64) >> 4) * 1024 + tid * 16,
                  (char*)&sbuf[cb ^ 1][0] + tid * 16);
            gll16(gsrc + (size_t)((kt + 64) >> 4) * 1024 + tid * 16,
                  (char*)&sbuf[cb ^ 1][256] + tid * 16);
        }
        const half_t* sph = (const half_t*)&sbuf[cb][0];
        const unsigned short* sg = (const unsigned short*)&sbuf[cb][256];
#pragma unroll
        for (int kf = 0; kf < 4; kf++) {
            half8v phA = *(const half8v*)(sph + kf * 512 + lane * 8);
            short8v g8 = *(const short8v*)(sg + kf * 512 + lane * 8);
            short4v ga0 = __builtin_shufflevector(g8, g8, 0, 1, 2, 3);
            short4v ga1 = __builtin_shufflevector(g8, g8, 4, 5, 6, 7);
            f32x4 s = __builtin_amdgcn_mfma_f32_16x16x32_f16(phA, th, z, 0, 0, 0);
            float p0 = __builtin_amdgcn_exp2f(s[0]);
            float p1 = __builtin_amdgcn_exp2f(s[1]);
            float p2 = __builtin_amdgcn_exp2f(s[2]);
            float p3 = __builtin_amdgcn_exp2f(s[3]);
            union { short4v s4; uint2 u2; } pb;
            pb.u2.x = pack_bf(p0, p1);
            pb.u2.y = pack_bf(p2, p3);
            acc0 = __builtin_amdgcn_mfma_f32_16x16x16bf16_1k(ga0, pb.s4, acc0, 0, 0, 0);
            acc1 = __builtin_amdgcn_mfma_f32_16x16x16bf16_1k(ga1, pb.s4, acc1, 0, 0, 0);
            accd = __builtin_amdgcn_mfma_f32_16x16x16bf16_1k(ones, pb.s4, accd, 0, 0, 0);
        }
        __syncthreads();
        cb ^= 1;
    }

    // denominator: row0 of accd -> quad==0 lanes, reg 0 (q = qbase + l15)
    if (quad == 0) Sden[(size_t)(b * KC + kc) * Ln + qbase + l15] = accd[0];

    // transpose acc -> [q][c] rows via padded per-wave LDS (rows 40 u16 = 80B)
    unsigned short* tbuf = (unsigned short*)&sbuf[0][0] + widx * 640;
    *(unsigned*)&tbuf[l15 * 40 + quad * 4]      = pack_bf(acc0[0], acc0[1]);
    *(unsigned*)&tbuf[l15 * 40 + quad * 4 + 2]  = pack_bf(acc0[2], acc0[3]);
    *(unsigned*)&tbuf[l15 * 40 + 16 + quad * 4]     = pack_bf(acc1[0], acc1[1]);
    *(unsigned*)&tbuf[l15 * 40 + 16 + quad * 4 + 2] = pack_bf(acc1[2], acc1[3]);
    __syncthreads();
    {
        int ql = lane >> 2, cq = (lane & 3) * 8;
        uint4 v = *(const uint4*)&tbuf[ql * 40 + cq];
        *(uint4*)(part + ((size_t)(b * KC + kc) * Ln + qbase + ql) * 32 + cq) = v;
    }
}

// ---------------------------------------------------------------------------
// merge (fused): ybar = sum_kc part / sum_kc Sden (coalesced uint4 loads),
// then out[b][c][l] = W*ybar + W_b + x via 16x16x32 MFMA; W converted from
// global directly. Grid Bn*64 x 256.
// ---------------------------------------------------------------------------
__global__ __launch_bounds__(256) void merge_kernel(
        const unsigned short* __restrict__ part, const float* __restrict__ Sden,
        const float* __restrict__ W_w, const float* __restrict__ W_b,
        const float* __restrict__ x, float* __restrict__ out, int KC) {
    int tid = threadIdx.x, lane = tid & 63, widx = tid >> 6;
    int l15 = lane & 15, quad = lane >> 4;
    int b = blockIdx.x >> 6;
    int t16 = (blockIdx.x & 63) * 4 + widx;
    int l = (t16 << 4) + l15;

    float den = 0.f;
    for (int kc = 0; kc < KC; kc++) den += Sden[(size_t)(b * KC + kc) * Ln + l];
    float inv = 1.f / den;

    float num[8] = {0.f, 0.f, 0.f, 0.f, 0.f, 0.f, 0.f, 0.f};
    for (int kc = 0; kc < KC; kc++) {
        uint4 v = *(const uint4*)&part[((size_t)(b * KC + kc) * Ln + l) * 32 + quad * 8];
        unsigned vv[4] = {v.x, v.y, v.z, v.w};
#pragma unroll
        for (int t = 0; t < 4; t++) {
            num[2 * t]     += __uint_as_float(vv[t] << 16);
            num[2 * t + 1] += __uint_as_float(vv[t] & 0xffff0000u);
        }
    }
    half_t yh[8];
#pragma unroll
    for (int j = 0; j < 8; j++) yh[j] = (half_t)(num[j] * inv);
    half8v yB;
    __builtin_memcpy(&yB, yh, 16);

    const f32x4 z = {0.f, 0.f, 0.f, 0.f};
    f32x4 acc[4];
#pragma unroll
    for (int mf = 0; mf < 4; mf++) {
        half8v wA = cvt8(&W_w[(mf * 16 + l15) * 32 + quad * 8], 1.0f);
        acc[mf] = __builtin_amdgcn_mfma_f32_16x16x32_f16(wA, yB, z, 0, 0, 0);
    }
#pragma unroll
    for (int mf = 0; mf < 4; mf++) {
        float4 bv = *(const float4*)&W_b[mf * 16 + quad * 4];
#pragma unroll
        for (int r = 0; r < 4; r++) {
            int c = mf * 16 + quad * 4 + r;
            size_t idx = (size_t)(b * 64 + c) * Ln + l;
            float bb = (r == 0) ? bv.x : (r == 1) ? bv.y : (r == 2) ? bv.z : bv.w;
            out[idx] = acc[mf][r] + bb + x[idx];
        }
    }
}

extern "C" void kernel_launch(void* const* d_in, const int* in_sizes, int n_in,
                              void* d_out, int out_size, void* d_ws, size_t ws_size,
                              hipStream_t stream) {
    const float* x    = (const float*)d_in[0];
    const float* g_w  = (const float*)d_in[1];
    const float* g_b  = (const float*)d_in[2];
    const float* th_w = (const float*)d_in[3];
    const float* th_b = (const float*)d_in[4];
    const float* ph_w = (const float*)d_in[5];
    const float* ph_b = (const float*)d_in[6];
    const float* W_w  = (const float*)d_in[7];
    const float* W_b  = (const float*)d_in[8];
    float* out = (float*)d_out;

    char* w = (char*)d_ws;
    const size_t off_th   = 0;                 // 1 MB (4*256*64*8*2)
    const size_t off_ph   = 1048576;           // 1 MB
    const size_t off_g    = 2097152;           // 1 MB
    const size_t off_Sden = 3145728;           // KC*Bn*Ln*4

    int KC = 16;
    size_t off_part = 0;
    while (true) {
        off_part = off_Sden + (size_t)KC * (Bn * Ln * 4);
        off_part = (off_part + 255) & ~(size_t)255;
        size_t need = off_part + (size_t)KC * ((size_t)Bn * Ln * 32 * 2);
        if (need <= ws_size || KC == 1) break;
        KC >>= 1;
    }

    half_t* thfrag = (half_t*)(w + off_th);
    half_t* phfrag = (half_t*)(w + off_ph);
    unsigned short* gfrag = (unsigned short*)(w + off_g);
    float* Sden    = (float*)(w + off_Sden);
    unsigned short* part = (unsigned short*)(w + off_part);

    int CH = Ln / KC;

    proj_kernel<<<Bn * 64, 192, 0, stream>>>(x, g_w, g_b, th_w, th_b, ph_w, ph_b,
                                             thfrag, phfrag, gfrag);
    attn_kernel<<<Bn * 64 * KC, 256, 0, stream>>>(thfrag, phfrag, gfrag, part, Sden,
                                                  KC, CH);
    merge_kernel<<<Bn * 64, 256, 0, stream>>>(part, Sden, W_w, W_b, x, out, KC);
}

// Round 8
// 98.454 us; speedup vs baseline: 1.0784x; 1.0784x over previous
//
#include <hip/hip_runtime.h>

#define Bn 4
#define Cdim 64
#define INTER 32
#define Ln 4096
#define LOG2E 1.44269504088896340736f

typedef _Float16 half_t;
typedef __attribute__((ext_vector_type(8))) _Float16 half8v;
typedef __attribute__((ext_vector_type(4))) short short4v;
typedef __attribute__((ext_vector_type(8))) short short8v;
typedef __attribute__((ext_vector_type(4))) float f32x4;

__device__ __forceinline__ unsigned short f2bf(float f) {
    unsigned u = __float_as_uint(f);
    u += 0x7fffu + ((u >> 16) & 1u);
    return (unsigned short)(u >> 16);
}
// rounded pack (epilogue)
__device__ __forceinline__ unsigned pack_bf(float a, float b) {
    unsigned ua = __float_as_uint(a) + 0x8000u;
    unsigned ub = __float_as_uint(b) + 0x8000u;
    return __builtin_amdgcn_perm(ub, ua, 0x07060302);
}
// truncating pack (hot loop: 1 VALU op)
__device__ __forceinline__ unsigned pack_bf_t(float a, float b) {
    return __builtin_amdgcn_perm(__float_as_uint(b), __float_as_uint(a), 0x07060302);
}
__device__ __forceinline__ void gll16(const void* g, void* l) {
    __builtin_amdgcn_global_load_lds(
        (const __attribute__((address_space(1))) unsigned int*)g,
        (__attribute__((address_space(3))) unsigned int*)l, 16, 0, 0);
}
__device__ __forceinline__ half8v cvt8(const float* p, float scale) {
    float4 f0 = *(const float4*)p;
    float4 f1 = *(const float4*)(p + 4);
    half_t h[8];
    h[0] = (half_t)(f0.x * scale); h[1] = (half_t)(f0.y * scale);
    h[2] = (half_t)(f0.z * scale); h[3] = (half_t)(f0.w * scale);
    h[4] = (half_t)(f1.x * scale); h[5] = (half_t)(f1.y * scale);
    h[6] = (half_t)(f1.z * scale); h[7] = (half_t)(f1.w * scale);
    half8v r;
    __builtin_memcpy(&r, h, 16);
    return r;
}

// ---------------------------------------------------------------------------
// proj (MFMA): [96ch][64l] = W * x-tile; weights converted from global.
// Grid Bn*64 x 256 (waves: 0=theta 1=phi 2=g, 3=staging helper only).
// Outputs in MFMA fragment layout:
//   thfrag/phfrag: [b][l16][lane][8 f16], gfrag: [b][k16][lane][8 bf16].
// ---------------------------------------------------------------------------
__global__ __launch_bounds__(256) void proj_kernel(
        const float* __restrict__ x,
        const float* __restrict__ g_w, const float* __restrict__ g_b,
        const float* __restrict__ th_w, const float* __restrict__ th_b,
        const float* __restrict__ ph_w, const float* __restrict__ ph_b,
        half_t* __restrict__ thfrag, half_t* __restrict__ phfrag,
        unsigned short* __restrict__ gfrag) {
    __shared__ half_t sx[64][72];        // [l][c]; 144B rows
    __shared__ unsigned short sg[2048];  // g-frag staging (4KB)
    int tid = threadIdx.x;
    int b = blockIdx.x >> 6;
    int l0 = (blockIdx.x & 63) << 6;

#pragma unroll
    for (int p = 0; p < 4; p++) {
        int i = tid + p * 256;
        int c = i >> 4, lq = (i & 15) << 2;
        float4 v = *(const float4*)&x[(size_t)(b * 64 + c) * Ln + l0 + lq];
        sx[lq + 0][c] = (half_t)v.x;
        sx[lq + 1][c] = (half_t)v.y;
        sx[lq + 2][c] = (half_t)v.z;
        sx[lq + 3][c] = (half_t)v.w;
    }
    __syncthreads();

    int lane = tid & 63, grp = tid >> 6;
    if (grp == 3) return;
    int l15 = lane & 15, quad = lane >> 4;

    const float* Wsrc = (grp == 0) ? th_w : (grp == 1) ? ph_w : g_w;
    const float* bsrc = (grp == 0) ? th_b : (grp == 1) ? ph_b : g_b;
    float scale = (grp == 0) ? LOG2E : 1.0f;

    half8v wA[2][2];
#pragma unroll
    for (int mf = 0; mf < 2; mf++)
#pragma unroll
        for (int kk = 0; kk < 2; kk++)
            wA[mf][kk] = cvt8(&Wsrc[(mf * 16 + l15) * 64 + kk * 32 + quad * 8], scale);
    half8v xB[4][2];
#pragma unroll
    for (int nf = 0; nf < 4; nf++)
#pragma unroll
        for (int kk = 0; kk < 2; kk++)
            xB[nf][kk] = *(const half8v*)&sx[nf * 16 + l15][kk * 32 + quad * 8];

    f32x4 acc[2][4];
    const f32x4 z = {0.f, 0.f, 0.f, 0.f};
#pragma unroll
    for (int mf = 0; mf < 2; mf++)
#pragma unroll
        for (int nf = 0; nf < 4; nf++) {
            f32x4 a = __builtin_amdgcn_mfma_f32_16x16x32_f16(wA[mf][0], xB[nf][0], z, 0, 0, 0);
            acc[mf][nf] = __builtin_amdgcn_mfma_f32_16x16x32_f16(wA[mf][1], xB[nf][1], a, 0, 0, 0);
        }
#pragma unroll
    for (int mf = 0; mf < 2; mf++) {
        float4 bv = *(const float4*)&bsrc[mf * 16 + quad * 4];
        float s0 = bv.x * scale, s1 = bv.y * scale, s2 = bv.z * scale, s3 = bv.w * scale;
#pragma unroll
        for (int nf = 0; nf < 4; nf++) {
            acc[mf][nf][0] += s0; acc[mf][nf][1] += s1;
            acc[mf][nf][2] += s2; acc[mf][nf][3] += s3;
        }
    }

    if (grp < 2) {
        half_t* F = (grp == 0) ? thfrag : phfrag;
#pragma unroll
        for (int mf = 0; mf < 2; mf++)
#pragma unroll
            for (int nf = 0; nf < 4; nf++) {
                half_t h[4];
                h[0] = (half_t)acc[mf][nf][0]; h[1] = (half_t)acc[mf][nf][1];
                h[2] = (half_t)acc[mf][nf][2]; h[3] = (half_t)acc[mf][nf][3];
                uint2 v;
                __builtin_memcpy(&v, h, 8);
                size_t u = (size_t)(b * 256 + (l0 >> 4) + nf) * 64 +
                           l15 + 16 * (mf * 2 + (quad >> 1));
                *(uint2*)(F + u * 8 + (quad & 1) * 4) = v;
            }
    } else {
#pragma unroll
        for (int mf = 0; mf < 2; mf++)
#pragma unroll
            for (int nf = 0; nf < 4; nf++)
#pragma unroll
                for (int r = 0; r < 4; r++) {
                    int lu = nf * 64 + (quad * 4 + r) + 16 * (l15 >> 2);
                    sg[lu * 8 + mf * 4 + (l15 & 3)] = f2bf(acc[mf][nf][r]);
                }
        __builtin_amdgcn_s_waitcnt(0);
        size_t base = (size_t)(b * 256 + (l0 >> 4)) * 512;
#pragma unroll
        for (int s = 0; s < 4; s++) {
            int i = lane + s * 64;
            uint4 v = ((const uint4*)sg)[i];
            *(uint4*)(gfrag + base + (size_t)i * 8) = v;
        }
    }
}

// ---------------------------------------------------------------------------
// attn: 32 q per wave, KC=4 (512 blocks, 2/CU). Block-staged LDS (dbuf,
// global_load_lds 16B). Truncating bf16 pack feeds PV directly (S C-layout ==
// K=16 PV B-layout). Denominator on MFMA pipe (ones-row). Epilogue: per-wave
// LDS transpose -> part as coalesced [b][kc][q][c32] rows.
// ---------------------------------------------------------------------------
__global__ __launch_bounds__(256, 2) void attn_kernel(
        const half_t* __restrict__ thfrag, const half_t* __restrict__ phfrag,
        const unsigned short* __restrict__ gfrag,
        unsigned short* __restrict__ part, float* __restrict__ Sden,
        int KC, int CH) {
    __shared__ uint4 sbuf[2][512];   // 16KB: [buf][phi 4KB | g 4KB]

    int tid = threadIdx.x, lane = tid & 63, widx = tid >> 6;
    int l15 = lane & 15, quad = lane >> 4;

    int blk = blockIdx.x;
    int b = blk / (32 * KC);
    int rem = blk % (32 * KC);
    int qblk = rem / KC, kc = rem % KC;
    int qbase = qblk * 128 + widx * 32;
    int k0 = kc * CH;

    half8v th[2];
#pragma unroll
    for (int qf = 0; qf < 2; qf++)
        th[qf] = *(const half8v*)(thfrag +
                                  ((size_t)(b * 256 + (qbase >> 4) + qf) * 64 + lane) * 8);

    unsigned short oh = (l15 == 0) ? 0x3F80 : 0;
    short4v ones;
    ones[0] = (short)oh; ones[1] = (short)oh; ones[2] = (short)oh; ones[3] = (short)oh;

    f32x4 acc[2][2], accd[2];
#pragma unroll
    for (int qf = 0; qf < 2; qf++) {
        acc[qf][0] = (f32x4){0.f, 0.f, 0.f, 0.f};
        acc[qf][1] = (f32x4){0.f, 0.f, 0.f, 0.f};
        accd[qf]   = (f32x4){0.f, 0.f, 0.f, 0.f};
    }

    const char* phsrc = (const char*)(phfrag + (size_t)b * 256 * 512);
    const char* gsrc  = (const char*)(gfrag + (size_t)b * 256 * 512);
    const f32x4 z = {0.f, 0.f, 0.f, 0.f};

    gll16(phsrc + (size_t)(k0 >> 4) * 1024 + tid * 16, (char*)&sbuf[0][0] + tid * 16);
    gll16(gsrc + (size_t)(k0 >> 4) * 1024 + tid * 16, (char*)&sbuf[0][256] + tid * 16);
    __syncthreads();

    int cb = 0;
    for (int kt = k0; kt < k0 + CH; kt += 64) {
        if (kt + 64 < k0 + CH) {
            gll16(phsrc + (size_t)((kt + 64) >> 4) * 1024 + tid * 16,
                  (char*)&sbuf[cb ^ 1][0] + tid * 16);
            gll16(gsrc + (size_t)((kt + 64) >> 4) * 1024 + tid * 16,
                  (char*)&sbuf[cb ^ 1][256] + tid * 16);
        }
        const half_t* sph = (const half_t*)&sbuf[cb][0];
        const unsigned short* sg = (const unsigned short*)&sbuf[cb][256];
#pragma unroll
        for (int kf = 0; kf < 4; kf++) {
            half8v phA = *(const half8v*)(sph + kf * 512 + lane * 8);
            short8v g8 = *(const short8v*)(sg + kf * 512 + lane * 8);
            short4v ga0 = __builtin_shufflevector(g8, g8, 0, 1, 2, 3);
            short4v ga1 = __builtin_shufflevector(g8, g8, 4, 5, 6, 7);
#pragma unroll
            for (int qf = 0; qf < 2; qf++) {
                f32x4 s = __builtin_amdgcn_mfma_f32_16x16x32_f16(phA, th[qf], z, 0, 0, 0);
                float p0 = __builtin_amdgcn_exp2f(s[0]);
                float p1 = __builtin_amdgcn_exp2f(s[1]);
                float p2 = __builtin_amdgcn_exp2f(s[2]);
                float p3 = __builtin_amdgcn_exp2f(s[3]);
                union { short4v s4; uint2 u2; } pb;
                pb.u2.x = pack_bf_t(p0, p1);
                pb.u2.y = pack_bf_t(p2, p3);
                acc[qf][0] = __builtin_amdgcn_mfma_f32_16x16x16bf16_1k(ga0, pb.s4,
                                                                      acc[qf][0], 0, 0, 0);
                acc[qf][1] = __builtin_amdgcn_mfma_f32_16x16x16bf16_1k(ga1, pb.s4,
                                                                      acc[qf][1], 0, 0, 0);
                accd[qf] = __builtin_amdgcn_mfma_f32_16x16x16bf16_1k(ones, pb.s4,
                                                                    accd[qf], 0, 0, 0);
            }
        }
        __syncthreads();
        cb ^= 1;
    }

    // denominator: row0 of accd (quad==0 lanes, reg 0); q = qbase + qf*16 + l15
    size_t sb = (size_t)(b * KC + kc) * Ln + qbase;
    if (quad == 0) {
        Sden[sb + l15] = accd[0][0];
        Sden[sb + 16 + l15] = accd[1][0];
    }

    // transpose acc -> [q][c32] rows via per-wave padded LDS (row = 40 u16)
    unsigned short* tb = (unsigned short*)&sbuf[0][0] + widx * 1280;
#pragma unroll
    for (int qf = 0; qf < 2; qf++) {
        int qr = qf * 16 + l15;
#pragma unroll
        for (int cf = 0; cf < 2; cf++) {
            uint2 v;
            v.x = pack_bf(acc[qf][cf][0], acc[qf][cf][1]);
            v.y = pack_bf(acc[qf][cf][2], acc[qf][cf][3]);
            *(uint2*)&tb[qr * 40 + cf * 16 + quad * 4] = v;
        }
    }
    __builtin_amdgcn_s_waitcnt(0);
    {
        int r = lane >> 1, h = lane & 1;        // row 0..31, 32B half
        uint4 v0 = *(const uint4*)&tb[r * 40 + h * 16];
        uint4 v1 = *(const uint4*)&tb[r * 40 + h * 16 + 8];
        unsigned short* dst = part + ((size_t)(b * KC + kc) * Ln + qbase + r) * 32 + h * 16;
        *(uint4*)dst = v0;
        *(uint4*)(dst + 8) = v1;
    }
}

// ---------------------------------------------------------------------------
// merge (fused): ybar = sum_kc part / sum_kc Sden (coalesced uint4 loads),
// out[b][c][l] = W*ybar + W_b + x via 16x16x32 MFMA. Grid Bn*64 x 256.
// ---------------------------------------------------------------------------
__global__ __launch_bounds__(256) void merge_kernel(
        const unsigned short* __restrict__ part, const float* __restrict__ Sden,
        const float* __restrict__ W_w, const float* __restrict__ W_b,
        const float* __restrict__ x, float* __restrict__ out, int KC) {
    int tid = threadIdx.x, lane = tid & 63, widx = tid >> 6;
    int l15 = lane & 15, quad = lane >> 4;
    int b = blockIdx.x >> 6;
    int t16 = (blockIdx.x & 63) * 4 + widx;
    int l = (t16 << 4) + l15;

    float den = 0.f;
    for (int kc = 0; kc < KC; kc++) den += Sden[(size_t)(b * KC + kc) * Ln + l];
    float inv = 1.f / den;

    float num[8] = {0.f, 0.f, 0.f, 0.f, 0.f, 0.f, 0.f, 0.f};
    for (int kc = 0; kc < KC; kc++) {
        uint4 v = *(const uint4*)&part[((size_t)(b * KC + kc) * Ln + l) * 32 + quad * 8];
        unsigned vv[4] = {v.x, v.y, v.z, v.w};
#pragma unroll
        for (int t = 0; t < 4; t++) {
            num[2 * t]     += __uint_as_float(vv[t] << 16);
            num[2 * t + 1] += __uint_as_float(vv[t] & 0xffff0000u);
        }
    }
    half_t yh[8];
#pragma unroll
    for (int j = 0; j < 8; j++) yh[j] = (half_t)(num[j] * inv);
    half8v yB;
    __builtin_memcpy(&yB, yh, 16);

    const f32x4 z = {0.f, 0.f, 0.f, 0.f};
    f32x4 acc[4];
#pragma unroll
    for (int mf = 0; mf < 4; mf++) {
        half8v wA = cvt8(&W_w[(mf * 16 + l15) * 32 + quad * 8], 1.0f);
        acc[mf] = __builtin_amdgcn_mfma_f32_16x16x32_f16(wA, yB, z, 0, 0, 0);
    }
#pragma unroll
    for (int mf = 0; mf < 4; mf++) {
        float4 bv = *(const float4*)&W_b[mf * 16 + quad * 4];
#pragma unroll
        for (int r = 0; r < 4; r++) {
            int c = mf * 16 + quad * 4 + r;
            size_t idx = (size_t)(b * 64 + c) * Ln + l;
            float bb = (r == 0) ? bv.x : (r == 1) ? bv.y : (r == 2) ? bv.z : bv.w;
            out[idx] = acc[mf][r] + bb + x[idx];
        }
    }
}

extern "C" void kernel_launch(void* const* d_in, const int* in_sizes, int n_in,
                              void* d_out, int out_size, void* d_ws, size_t ws_size,
                              hipStream_t stream) {
    const float* x    = (const float*)d_in[0];
    const float* g_w  = (const float*)d_in[1];
    const float* g_b  = (const float*)d_in[2];
    const float* th_w = (const float*)d_in[3];
    const float* th_b = (const float*)d_in[4];
    const float* ph_w = (const float*)d_in[5];
    const float* ph_b = (const float*)d_in[6];
    const float* W_w  = (const float*)d_in[7];
    const float* W_b  = (const float*)d_in[8];
    float* out = (float*)d_out;

    char* w = (char*)d_ws;
    const size_t off_th   = 0;                 // 1 MB (4*256*64*8*2)
    const size_t off_ph   = 1048576;           // 1 MB
    const size_t off_g    = 2097152;           // 1 MB
    const size_t off_Sden = 3145728;           // KC*Bn*Ln*4

    int KC = 4;
    size_t off_part = 0;
    while (true) {
        off_part = off_Sden + (size_t)KC * (Bn * Ln * 4);
        off_part = (off_part + 255) & ~(size_t)255;
        size_t need = off_part + (size_t)KC * ((size_t)Bn * Ln * 32 * 2);
        if (need <= ws_size || KC == 1) break;
        KC >>= 1;
    }

    half_t* thfrag = (half_t*)(w + off_th);
    half_t* phfrag = (half_t*)(w + off_ph);
    unsigned short* gfrag = (unsigned short*)(w + off_g);
    float* Sden    = (float*)(w + off_Sden);
    unsigned short* part = (unsigned short*)(w + off_part);

    int CH = Ln / KC;

    proj_kernel<<<Bn * 64, 256, 0, stream>>>(x, g_w, g_b, th_w, th_b, ph_w, ph_b,
                                             thfrag, phfrag, gfrag);
    attn_kernel<<<Bn * 32 * KC, 256, 0, stream>>>(thfrag, phfrag, gfrag, part, Sden,
                                                  KC, CH);
    merge_kernel<<<Bn * 64, 256, 0, stream>>>(part, Sden, W_w, W_b, x, out, KC);
}